// Round 7
// baseline (224.308 us; speedup 1.0000x reference)
//
#include <hip/hip_runtime.h>
#include <stdint.h>

// ---------------------------------------------------------------------------
// HandcraftedKeyModel: clamped-decay scan (12 keys) + per-step [12]@[12,84].
//
// h -> min(d*h + b, 5) closes under composition as (A,B,C): h -> min(A*h+B,C).
// Two-kernel structure (was 3; node-boundary + low-occupancy KB removed):
//   K1 : 64 blocks x 128 thr. Thread t composes chunk c=blk*128+t (64 steps)
//        -> (B[12],C[12]); block-local exclusive scan over its 128 chunks
//        emits loc[c]{lB,lC} (prefix within group), agg[g]{B,C} (group
//        aggregate), and Atab[j]=A64^j (block 0 only).
//   KC : one block per chunk. Lanes 0..11 redundantly scan the <=63 group
//        aggregates (L2-hot) -> group-start value v; combine with local
//        prefix: hstart = min(Atab[j]*v + lB, lC); replay 64 steps exactly
//        into LDS heats[64][12]; then 252 threads compute out = heats @ W
//        (W quads in 48 VGPRs), 1 KiB contiguous float4 stores per wave.
// ---------------------------------------------------------------------------

#define NKEY 12
#define NOUT 84           // 7 modes * 12 scales
#define LC   64           // steps per chunk
#define CPG  128          // chunks per group
#define NGRP 64           // groups (8192/128)

constexpr double DECAYD = 0.9995001249791693;    // exp(-0.0005)
constexpr float  DECAYF = (float)DECAYD;
constexpr float  BIGC   = 1e30f;

constexpr float cpowf(int n) {        // d^n via double chain -> float
    double r = 1.0;
    for (int i = 0; i < n; ++i) r *= DECAYD;
    return (float)r;
}
constexpr float A64 = cpowf(LC);          // d^64    (chunk A)
constexpr float AG  = cpowf(LC * CPG);    // d^8192  (group A)

// ------------- K1: chunk compose + in-block group scan ---------------------
__global__ __launch_bounds__(CPG) void k1(const int* __restrict__ seq,
                                          float* __restrict__ loc,
                                          float* __restrict__ agg,
                                          float* __restrict__ Atab) {
    __shared__ float LB[CPG][13], LX[CPG][13];   // +1 pad: conflict-free
    const int t = threadIdx.x;
    const int c = blockIdx.x * CPG + t;          // chunk id
    const float D = DECAYF;
    float B[NKEY], C[NKEY];
#pragma unroll
    for (int k = 0; k < NKEY; ++k) { B[k] = 0.0f; C[k] = BIGC; }

    const int4* s4 = reinterpret_cast<const int4*>(seq) + c * (LC / 4);
    for (int q = 0; q < LC / 4; ++q) {
        int4 v4 = s4[q];
        int vv[4] = {v4.x, v4.y, v4.z, v4.w};
#pragma unroll
        for (int u = 0; u < 4; ++u) {
            int note = vv[u];
            bool valid = note > -10000;
            int m = note % NKEY; if (m < 0) m += NKEY;
#pragma unroll
            for (int k = 0; k < NKEY; ++k) {
                float b = (valid && (m == k)) ? 1.0f : 0.0f;
                B[k] = fmaf(B[k], D, b);
                C[k] = fminf(fmaf(C[k], D, b), 5.0f);
            }
        }
    }
#pragma unroll
    for (int k = 0; k < NKEY; ++k) { LB[t][k] = B[k]; LX[t][k] = C[k]; }
    __syncthreads();

    // 12 lanes: exclusive scan over the group's 128 chunks.
    if (t < NKEY) {
        float b = 0.0f, cc = BIGC, a = 1.0f;
        const int base = blockIdx.x * CPG;
        const bool w0 = (blockIdx.x == 0) && (t == 0);
        for (int j = 0; j < CPG; ++j) {
            loc[(size_t)(base + j) * 24 + t]      = b;
            loc[(size_t)(base + j) * 24 + 12 + t] = cc;
            if (w0) Atab[j] = a;
            a *= A64;
            float b1 = LB[j][t], c1 = LX[j][t];
            b  = fmaf(A64, b, b1);
            cc = fminf(fmaf(A64, cc, b1), c1);
        }
        agg[blockIdx.x * 24 + t]      = b;
        agg[blockIdx.x * 24 + 12 + t] = cc;
    }
}

// ---------- KC: group-scan + local combine + replay + [12]@[12,84] ---------
__global__ __launch_bounds__(256) void kC(const int* __restrict__ seq,
                                          const float* __restrict__ W,
                                          const float* __restrict__ loc,
                                          const float* __restrict__ agg,
                                          const float* __restrict__ Atab,
                                          float* __restrict__ out) {
    __shared__ float heats[LC][NKEY];   // 3 KiB, row stride 48 B
    __shared__ int   notes[LC];
    const int c   = blockIdx.x;
    const int tid = threadIdx.x;
    const int q = tid % 21;             // column quad 0..20
    const int r = tid / 21;             // row class 0..12 (12 => idle tail)

    float4 w4[NKEY];                    // 48 VGPRs of W quads
#pragma unroll
    for (int k = 0; k < NKEY; ++k)
        w4[k] = reinterpret_cast<const float4*>(W + k * NOUT)[q];

    if (tid < LC / 4) {
        int4 v = reinterpret_cast<const int4*>(seq + (size_t)c * LC)[tid];
        reinterpret_cast<int4*>(notes)[tid] = v;
    }
    if (tid < NKEY) {
        // group-start value: scan aggregates of groups 0..g-1 (L2-hot, 6 KB)
        const int g = c >> 7, j = c & (CPG - 1);
        float v = 0.0f;
        for (int gp = 0; gp < g; ++gp)
            v = fminf(fmaf(AG, v, agg[gp * 24 + tid]), agg[gp * 24 + 12 + tid]);
        // combine with local (within-group) exclusive prefix
        float h = fminf(fmaf(Atab[j], v, loc[(size_t)c * 24 + tid]),
                        loc[(size_t)c * 24 + 12 + tid]);
        // exact 64-step replay
        const float D = DECAYF;
        for (int i = 0; i < LC; ++i) {
            int note = notes[i];        // same-wave LDS, ordered
            bool valid = note > -10000;
            int m = note % NKEY; if (m < 0) m += NKEY;
            float b = (valid && (m == tid)) ? 1.0f : 0.0f;
            h = fminf(fmaf(h, D, b), 5.0f);
            heats[i][tid] = h;
        }
    }
    __syncthreads();
    if (tid >= 252) return;

    float* const op = out + (size_t)c * (LC * NOUT) + q * 4;

    auto emit_row = [&](int row) {
        const float4* hv = reinterpret_cast<const float4*>(&heats[row][0]);
        float4 h0 = hv[0], h1 = hv[1], h2 = hv[2];
        const float hk[NKEY] = {h0.x, h0.y, h0.z, h0.w,
                                h1.x, h1.y, h1.z, h1.w,
                                h2.x, h2.y, h2.z, h2.w};
        float4 o; o.x = o.y = o.z = o.w = 0.0f;
#pragma unroll
        for (int k = 0; k < NKEY; ++k) {
            o.x = fmaf(hk[k], w4[k].x, o.x);
            o.y = fmaf(hk[k], w4[k].y, o.y);
            o.z = fmaf(hk[k], w4[k].z, o.z);
            o.w = fmaf(hk[k], w4[k].w, o.w);
        }
        *reinterpret_cast<float4*>(op + row * NOUT) = o;
    };

#pragma unroll
    for (int s = 0; s < 5; ++s) emit_row(r + 12 * s);  // rows 0..59
    if (r < 4) emit_row(60 + r);                       // rows 60..63
}

// ---------------------------------------------------------------------------
extern "C" void kernel_launch(void* const* d_in, const int* in_sizes, int n_in,
                              void* d_out, int out_size, void* d_ws, size_t ws_size,
                              hipStream_t stream) {
    const int*   seq = (const int*)d_in[0];
    const float* W   = (const float*)d_in[1];
    float*       out = (float*)d_out;

    const int T  = in_sizes[0];     // 524288
    const int nc = T / LC;          // 8192 chunks

    float* loc  = (float*)d_ws;                    // [nc][24]  (786 KB)
    float* agg  = loc + (size_t)nc * 24;           // [64][24]  (6 KB)
    float* Atab = agg + (size_t)NGRP * 24;         // [128]     (512 B)

    hipLaunchKernelGGL(k1, dim3(NGRP), dim3(CPG), 0, stream,
                       seq, loc, agg, Atab);
    hipLaunchKernelGGL(kC, dim3(nc), dim3(256), 0, stream,
                       seq, W, loc, agg, Atab, out);
}

// Round 11
// 212.745 us; speedup vs baseline: 1.0544x; 1.0544x over previous
//
#include <hip/hip_runtime.h>
#include <stdint.h>

// ---------------------------------------------------------------------------
// HandcraftedKeyModel: clamped-decay scan (12 keys) + per-step [12]@[12,84].
//
// h -> min(d*h + b, 5) closes under composition as (A,B,C): h -> min(A*h+B,C).
// R6 3-kernel structure (best: 207us) with kC reworked to 4 chunks/block:
//   kA : per-64-step chunk compose -> Bc/Cc (k-major) + per-32-chunk group
//        totals via LDS -> BG/CG [12][256].
//   kB : one block PER KEY (12 blocks): super-compose(16x16) -> scan 16 ->
//        rewalk -> vstart[256] in LDS -> 256 threads walk 32 chunks each,
//        emitting hs[c][12] (value at every chunk start).
//   kC : one block per 4 chunks (2048 blocks). Each wave stages + replays
//        ONE chunk (4 parallel 64-step chains, lanes 0..11), then 252
//        threads compute out = heats @ W (W quads in 48 VGPRs) with
//        nontemporal float4 stores, 1 KiB contiguous per wave-store.
// ---------------------------------------------------------------------------

#define NKEY 12
#define NOUT 84           // 7 modes * 12 scales
#define LC   64           // steps per chunk
#define GSZ  32           // chunks per group (kA/kB)
#define NGRP 256          // groups (8192/32)
#define NSUP 16           // supers (256/16)
#define CPB  4            // chunks per kC block

typedef float f32x4 __attribute__((ext_vector_type(4)));  // nontemporal-ok

constexpr double DECAYD = 0.9995001249791693;    // exp(-0.0005)
constexpr float  DECAYF = (float)DECAYD;
constexpr float  BIGC   = 1e30f;

constexpr float cpowf(int n) {        // d^n via double chain -> float
    double r = 1.0;
    for (int i = 0; i < n; ++i) r *= DECAYD;
    return (float)r;
}
constexpr float A64 = cpowf(LC);              // d^64     (chunk A)
constexpr float AG  = cpowf(LC * GSZ);        // d^2048   (group A)
constexpr float AS  = cpowf(LC * GSZ * NSUP); // d^32768  (super A)

// ------------------- kA: chunk compose + group totals ----------------------
__global__ __launch_bounds__(128) void kA(const int* __restrict__ seq,
                                          float* __restrict__ Bc,
                                          float* __restrict__ Cc,
                                          float* __restrict__ BG,
                                          float* __restrict__ CG,
                                          int nc) {
    const int tid = threadIdx.x;
    const int c   = blockIdx.x * 128 + tid;      // chunk id
    const float D = DECAYF;
    float B[NKEY], C[NKEY];
#pragma unroll
    for (int k = 0; k < NKEY; ++k) { B[k] = 0.0f; C[k] = BIGC; }

    const int4* s4 = reinterpret_cast<const int4*>(seq) + c * (LC / 4);
    for (int q = 0; q < LC / 4; ++q) {
        int4 v4 = s4[q];
        int vv[4] = {v4.x, v4.y, v4.z, v4.w};
#pragma unroll
        for (int u = 0; u < 4; ++u) {
            int note = vv[u];
            bool valid = note > -10000;
            int m = note % NKEY; if (m < 0) m += NKEY;
#pragma unroll
            for (int k = 0; k < NKEY; ++k) {
                float b = (valid && (m == k)) ? 1.0f : 0.0f;
                B[k] = fmaf(B[k], D, b);
                C[k] = fminf(fmaf(C[k], D, b), 5.0f);
            }
        }
    }
    // coalesced k-major stores
#pragma unroll
    for (int k = 0; k < NKEY; ++k) {
        Bc[k * nc + c] = B[k];
        Cc[k * nc + c] = C[k];
    }

    // in-block group totals (128 chunks = 4 groups of 32)
    __shared__ float LB[128][NKEY], LX[128][NKEY];   // 12 KiB
#pragma unroll
    for (int k = 0; k < NKEY; ++k) { LB[tid][k] = B[k]; LX[tid][k] = C[k]; }
    __syncthreads();
    if (tid < 4 * NKEY) {
        const int Gl = tid / NKEY, k = tid % NKEY;
        float b = 0.0f, cc = BIGC;
        const int base = Gl * GSZ;
        for (int i = 0; i < GSZ; ++i) {
            float b1 = LB[base + i][k], c1 = LX[base + i][k];
            b  = fmaf(A64, b, b1);
            cc = fminf(fmaf(A64, cc, b1), c1);
        }
        const int G = blockIdx.x * 4 + Gl;
        BG[k * NGRP + G] = b;
        CG[k * NGRP + G] = cc;
    }
}

// ---------------- kB: per-key scan -> per-chunk start values ---------------
__global__ __launch_bounds__(256) void kB(const float* __restrict__ Bc,
                                          const float* __restrict__ Cc,
                                          const float* __restrict__ BG,
                                          const float* __restrict__ CG,
                                          float* __restrict__ hs,
                                          int nc) {
    const int k   = blockIdx.x;          // 0..11
    const int tid = threadIdx.x;
    __shared__ float SB[NSUP], SC[NSUP], PB[NSUP], PC[NSUP], VST[NGRP];

    if (tid < NSUP) {                    // super-compose (16 groups each)
        float b = 0.0f, c = BIGC;
        for (int i = 0; i < NGRP / NSUP; ++i) {
            const int G = tid * (NGRP / NSUP) + i;
            float b1 = BG[k * NGRP + G], c1 = CG[k * NGRP + G];
            b = fmaf(AG, b, b1);
            c = fminf(fmaf(AG, c, b1), c1);
        }
        SB[tid] = b; SC[tid] = c;
    }
    __syncthreads();
    if (tid == 0) {                      // scan 16 supers (exclusive)
        float b = 0.0f, c = BIGC;
        for (int s = 0; s < NSUP; ++s) {
            PB[s] = b; PC[s] = c;
            float b1 = SB[s], c1 = SC[s];
            b = fmaf(AS, b, b1);
            c = fminf(fmaf(AS, c, b1), c1);
        }
    }
    __syncthreads();
    if (tid < NSUP) {                    // rewalk supers -> group-start values
        float b = PB[tid], c = PC[tid];
        for (int i = 0; i < NGRP / NSUP; ++i) {
            const int G = tid * (NGRP / NSUP) + i;
            VST[G] = fminf(b, c);
            float b1 = BG[k * NGRP + G], c1 = CG[k * NGRP + G];
            b = fmaf(AG, b, b1);
            c = fminf(fmaf(AG, c, b1), c1);
        }
    }
    __syncthreads();
    {                                    // thread g walks group g's 32 chunks
        const int g = tid;
        float v = VST[g];
        const int c0 = g * GSZ;
        for (int i = 0; i < GSZ; ++i) {
            hs[(size_t)(c0 + i) * NKEY + k] = v;
            float b1 = Bc[k * nc + c0 + i], c1 = Cc[k * nc + c0 + i];
            v = fminf(fmaf(A64, v, b1), c1);
        }
    }
}

// ----------- kC: 4-chunk replay (one per wave) + [12]@[12,84] --------------
__global__ __launch_bounds__(256) void kC(const int* __restrict__ seq,
                                          const float* __restrict__ W,
                                          const float* __restrict__ hs,
                                          float* __restrict__ out) {
    __shared__ float heats[CPB * LC][NKEY];   // 12 KiB, row stride 48 B
    __shared__ int   notes[CPB * LC];         // 1 KiB
    const int sc   = blockIdx.x;              // superchunk (4 chunks)
    const int tid  = threadIdx.x;
    const int wv   = tid >> 6;                // wave 0..3 -> chunk 4*sc+wv
    const int lane = tid & 63;
    const int q = tid % 21;                   // column quad 0..20
    const int r = tid / 21;                   // row class 0..12 (>=12 idle)

    float4 w4[NKEY];                          // 48 VGPRs of W quads
#pragma unroll
    for (int k = 0; k < NKEY; ++k)
        w4[k] = reinterpret_cast<const float4*>(W + k * NOUT)[q];

    // per-wave staging of this wave's chunk (16 int4 = 64 notes)
    if (lane < LC / 4) {
        int4 v = reinterpret_cast<const int4*>(
                     seq + ((size_t)sc * CPB + wv) * LC)[lane];
        reinterpret_cast<int4*>(notes + wv * LC)[lane] = v;
    }
    // per-wave exact 64-step replay, lanes 0..11 (same-wave LDS, ordered)
    if (lane < NKEY) {
        float h = hs[((size_t)sc * CPB + wv) * NKEY + lane];
        const float D = DECAYF;
        const int nb = wv * LC;
#pragma unroll 8
        for (int i = 0; i < LC; ++i) {
            int note = notes[nb + i];
            bool valid = note > -10000;
            int m = note % NKEY; if (m < 0) m += NKEY;
            float b = (valid && (m == lane)) ? 1.0f : 0.0f;
            h = fminf(fmaf(h, D, b), 5.0f);
            heats[nb + i][lane] = h;
        }
    }
    __syncthreads();
    if (tid >= 252) return;

    float* const opb = out + (size_t)sc * (CPB * LC * NOUT) + q * 4;

    auto emit_row = [&](int grow) {           // grow in [0, 256)
        const float4* hv = reinterpret_cast<const float4*>(&heats[grow][0]);
        float4 h0 = hv[0], h1 = hv[1], h2 = hv[2];
        const float hk[NKEY] = {h0.x, h0.y, h0.z, h0.w,
                                h1.x, h1.y, h1.z, h1.w,
                                h2.x, h2.y, h2.z, h2.w};
        f32x4 o = {0.0f, 0.0f, 0.0f, 0.0f};
#pragma unroll
        for (int k = 0; k < NKEY; ++k) {
            o.x = fmaf(hk[k], w4[k].x, o.x);
            o.y = fmaf(hk[k], w4[k].y, o.y);
            o.z = fmaf(hk[k], w4[k].z, o.z);
            o.w = fmaf(hk[k], w4[k].w, o.w);
        }
        __builtin_nontemporal_store(o,
            reinterpret_cast<f32x4*>(opb + (size_t)grow * NOUT));
    };

#pragma unroll
    for (int ch = 0; ch < CPB; ++ch) {
        const int base = ch * LC;
#pragma unroll
        for (int s = 0; s < 5; ++s) emit_row(base + r + 12 * s);  // rows 0..59
        if (r < 4) emit_row(base + 60 + r);                       // rows 60..63
    }
}

// ---------------------------------------------------------------------------
extern "C" void kernel_launch(void* const* d_in, const int* in_sizes, int n_in,
                              void* d_out, int out_size, void* d_ws, size_t ws_size,
                              hipStream_t stream) {
    const int*   seq = (const int*)d_in[0];
    const float* W   = (const float*)d_in[1];
    float*       out = (float*)d_out;

    const int T  = in_sizes[0];     // 524288
    const int nc = T / LC;          // 8192 chunks

    float* Bc = (float*)d_ws;                      // [12][nc]
    float* Cc = Bc + (size_t)NKEY * nc;            // [12][nc]
    float* BG = Cc + (size_t)NKEY * nc;            // [12][256]
    float* CG = BG + (size_t)NKEY * NGRP;          // [12][256]
    float* hs = CG + (size_t)NKEY * NGRP;          // [nc][12]

    hipLaunchKernelGGL(kA, dim3(nc / 128), dim3(128), 0, stream,
                       seq, Bc, Cc, BG, CG, nc);
    hipLaunchKernelGGL(kB, dim3(NKEY), dim3(NGRP), 0, stream,
                       Bc, Cc, BG, CG, hs, nc);
    hipLaunchKernelGGL(kC, dim3(nc / CPB), dim3(256), 0, stream,
                       seq, W, hs, out);
}